// Round 2
// baseline (293.127 us; speedup 1.0000x reference)
//
#include <hip/hip_runtime.h>
#include <hip/hip_bf16.h>
#include <math.h>

// Problem constants
#define TT   4096     // T
#define BB   16       // B
#define NTOK 65536    // B*T
#define CIN  512      // IN_FEATS
#define EF   256      // EMBED_FEATS
#define NE   1024     // NUM_EMBED

typedef __attribute__((ext_vector_type(8))) short bf16x8;
typedef __attribute__((ext_vector_type(4))) float f32x4;

static __device__ __forceinline__ unsigned short f2bf(float f) {
  unsigned int u = __float_as_uint(f);
  u += 0x7fffu + ((u >> 16) & 1u);          // RNE
  return (unsigned short)(u >> 16);
}

// async global->LDS, 16B per lane; LDS dest is wave-uniform base + lane*16
#define GLL(gsrc, ldst) \
  __builtin_amdgcn_global_load_lds((const __attribute__((address_space(1))) void*)(gsrc), \
                                   (__attribute__((address_space(3))) void*)(ldst), 16, 0, 0)

// ---------------------------------------------------------------------------
// K0: convert proj_w -> bf16; embed -> bf16*(-2); e_norm[k] = ||embed_k||^2
// ---------------------------------------------------------------------------
__global__ __launch_bounds__(256) void k_prep(const float* __restrict__ Wf,
                                              const float* __restrict__ Ef,
                                              unsigned short* __restrict__ Wbf,
                                              unsigned short* __restrict__ Ebf,
                                              float* __restrict__ e_norm) {
  int bid = blockIdx.x;
  if (bid < 512) {                      // W: 256*512 = 131072 elems
    int i = bid * 256 + threadIdx.x;
    Wbf[i] = f2bf(Wf[i]);
  } else if (bid < 1536) {              // E scaled by -2 (exact): 262144 elems
    int i = (bid - 512) * 256 + threadIdx.x;
    Ebf[i] = f2bf(-2.0f * Ef[i]);
  } else {                              // e_norm: 256 blocks * 4 codes (1 wave/code)
    int w = threadIdx.x >> 6, l = threadIdx.x & 63;
    int k = (bid - 1536) * 4 + w;
    const float4 v4 = ((const float4*)(Ef + (size_t)k * EF))[l];
    float s = v4.x * v4.x + v4.y * v4.y + v4.z * v4.z + v4.w * v4.w;
    for (int off = 32; off; off >>= 1) s += __shfl_down(s, off);
    if (l == 0) e_norm[k] = s;
  }
}

// ---------------------------------------------------------------------------
// K1 (fused), 512 threads / 128 tokens per block, 512 blocks.
// NOTE launch_bounds: arg=2 -> 128 VGPR. KEEP arg=2.
//
// Counted-vmcnt discipline (lesson from the NaN round): a counted
// s_waitcnt is only sound if the vmem ISSUE order is pinned.  Two rules
// applied here:
//   (a) phase 1: sched_barrier(0) right after the GLL-W group, so the
//       v(ks+1) register prefetch (independent addrspace-1 reads) can
//       never hoist above the GLLs.  vmcnt(16) then provably retires
//       exactly the 4 W-GLLs.
//   (b) phase 3: the chunk loop's vmem stream is PURE GLL -- e_norm is
//       copied once into an LDS table (entab) in the prologue, so no
//       scalar load can interleave with the counted stream.  2 GLLs per
//       chunk, 3 rotating 16KB buffers, depth-1 prefetch, vmcnt(2).
//
//  phase1: x = in^T @ W^T, 8 ks iters, counted barriers (W stays the only
//          drained vmem; input prefetch rides across both barriers).
//  phase2: bias -> bf16 xs[128][256] swizzled; xsq += x^2.
//  phase3: af[2][8] in regs; 32 chunks x 32 codes; acc init = e_norm from
//          LDS table (bit-identical numerics to the 292us version).
//  phase4: argmin merge -> LDS fidx[128], hist, sse.
//  phase5: fused gather: embed[fidx] -> LDS transpose tile -> out[B][EF][TT].
// LDS 64 KB static -> 2 blocks/CU; VGPR ~110 -> no spills.
// ---------------------------------------------------------------------------
__global__ __launch_bounds__(512, 2) void k_fused(const float* __restrict__ in,
                                                  const unsigned short* __restrict__ Wbf,
                                                  const float* __restrict__ bias,
                                                  const unsigned short* __restrict__ Ebf,
                                                  const float* __restrict__ e_norm,
                                                  const float* __restrict__ embed,
                                                  unsigned int* __restrict__ hist,
                                                  float* __restrict__ sse,
                                                  float* __restrict__ out) {
  __shared__ unsigned short lds[32768];   // 64 KB
  unsigned short* as_ = lds;              // phase1 A [128 t][64 c]   16 KB
  unsigned short* bs  = lds + 8192;       // phase1 W [256 e][64 c]   32 KB
  unsigned short* xs  = lds;              // phase2   x [128 t][256 e] 64 KB

  int tid = threadIdx.x;
  int w = tid >> 6, l = tid & 63;
  int l15 = l & 15, quad = l >> 4;
  int tq = w & 1, eq = w >> 1;            // phase1 MFMA mapping
  int cg = w & 3, th = w >> 2;            // phase1 A-load mapping
  int tok0 = blockIdx.x * 128;
  const float* src = in + (size_t)(tok0 >> 12) * CIN * TT + (tok0 & 4095);

  // ------------------ phase 1: projection GEMM ------------------
  f32x4 acc[4][4];
#pragma unroll
  for (int a = 0; a < 4; ++a)
#pragma unroll
    for (int b = 0; b < 4; ++b) acc[a][b] = (f32x4){0.f, 0.f, 0.f, 0.f};

  float v[16];
  {
    const float* s0 = src + (size_t)(cg * 16) * TT + th * 64 + l;
#pragma unroll
    for (int i = 0; i < 16; ++i) v[i] = s0[(size_t)i * TT];
  }
  for (int ks = 0; ks < 8; ++ks) {
    int k0 = ks * 64;
    // W stage: 2048 16B chunks via GLL (reads of bs from ks-1 closed by the
    // raw barrier at the end of the previous iteration)
#pragma unroll
    for (int i = 0; i < 4; ++i) {
      int g = i * 512 + tid;
      int row = g >> 3, pc = g & 7, lc = pc ^ (row & 7);
      GLL(Wbf + (size_t)row * CIN + k0 + lc * 8, bs + g * 8);
    }
    // pin: nothing below may issue before the 4 GLLs (keeps them OLDEST)
    __builtin_amdgcn_sched_barrier(0);
    // A: convert current regs (compiler waits v(ks) with vmcnt(4), GLLs fly)
    int trow = th * 64 + l;
#pragma unroll
    for (int cc = 0; cc < 2; ++cc) {
      alignas(16) unsigned short tmp[8];
#pragma unroll
      for (int j = 0; j < 8; ++j) tmp[j] = f2bf(v[cc * 8 + j]);
      int c8 = cg * 2 + cc;
      int pc2 = c8 ^ (trow & 7);
      *(bf16x8*)(as_ + trow * 64 + pc2 * 8) = *(const bf16x8*)tmp;
    }
    if (ks < 7) {
      // prefetch next ks A BEFORE barrier1: 16 loads stay in flight across
      // both barriers and the whole MFMA section
      const float* s0 = src + (size_t)(k0 + 64 + cg * 16) * TT + th * 64 + l;
#pragma unroll
      for (int i = 0; i < 16; ++i) v[i] = s0[(size_t)i * TT];
      __builtin_amdgcn_sched_barrier(0);
      // outstanding = 4 GLL (oldest) + 16 v -> wait the GLLs only
      asm volatile("s_waitcnt vmcnt(16) lgkmcnt(0)\n\ts_barrier" ::: "memory");
    } else {
      asm volatile("s_waitcnt vmcnt(0) lgkmcnt(0)\n\ts_barrier" ::: "memory");
    }
#pragma unroll
    for (int kstep = 0; kstep < 2; ++kstep) {
      int ck = kstep * 4 + quad;
      bf16x8 af[4], bfr[4];
#pragma unroll
      for (int msub = 0; msub < 4; ++msub) {
        int row = tq * 64 + msub * 16 + l15;
        int pa = ck ^ (row & 7);
        af[msub] = *(const bf16x8*)(as_ + row * 64 + pa * 8);
      }
#pragma unroll
      for (int nsub = 0; nsub < 4; ++nsub) {
        int row = eq * 64 + nsub * 16 + l15;
        int pb = ck ^ (row & 7);
        bfr[nsub] = *(const bf16x8*)(bs + row * 64 + pb * 8);
      }
      __builtin_amdgcn_s_setprio(1);
#pragma unroll
      for (int msub = 0; msub < 4; ++msub)
#pragma unroll
        for (int nsub = 0; nsub < 4; ++nsub)
          acc[msub][nsub] = __builtin_amdgcn_mfma_f32_16x16x32_bf16(af[msub], bfr[nsub],
                                                                    acc[msub][nsub], 0, 0, 0);
      __builtin_amdgcn_s_setprio(0);
    }
    // raw barrier: own ds_reads completed (lgkm), v(ks+1) stays in flight
    asm volatile("s_waitcnt lgkmcnt(0)\n\ts_barrier" ::: "memory");
  }

  // ------------------ phase 2: bias + x -> LDS xs, xsq ------------------
  float xsq = 0.f;
#pragma unroll
  for (int nsub = 0; nsub < 4; ++nsub) {
    int e = eq * 64 + nsub * 16 + l15;
    float bv = bias[e];
    int cx = e >> 3;
#pragma unroll
    for (int msub = 0; msub < 4; ++msub)
#pragma unroll
      for (int reg = 0; reg < 4; ++reg) {
        int m = tq * 64 + msub * 16 + quad * 4 + reg;
        float x = acc[msub][nsub][reg] + bv;
        xsq += x * x;
        int pcx = cx ^ (m & 31);
        xs[m * 256 + pcx * 8 + (e & 7)] = f2bf(x);
      }
  }
  __syncthreads();

  // ------------------ phase 3: A-frags to regs, 32x32-code chunk stream ----
  int g3 = w & 3, h = w >> 2;             // h in 0..1 (16-code half per wave)
  bf16x8 af[2][8];
#pragma unroll
  for (int msub = 0; msub < 2; ++msub)
#pragma unroll
    for (int kst = 0; kst < 8; ++kst) {
      int row = g3 * 32 + msub * 16 + l15;
      int c32 = kst * 4 + quad;
      int pcx = c32 ^ (row & 31);
      af[msub][kst] = *(const bf16x8*)(xs + row * 256 + pcx * 8);
    }
  __syncthreads();   // xs dead; LDS -> 3 x 16KB code buffers + entab table

  // entab: full e_norm (1024 f32, 4 KB) at byte 49152 (just past buffer 2)
  float* entab = (float*)(lds + 24576);
  {
    float2 ev = *(const float2*)(e_norm + (tid << 1));
    *(float2*)(entab + (tid << 1)) = ev;   // compiler drains the load first
  }
  __builtin_amdgcn_sched_barrier(0);
  // stage chunk 0 into buffer 0 (the ONLY vmem ops from here on are GLLs)
#pragma unroll
  for (int i = 0; i < 2; ++i) {
    int g = i * 512 + tid;
    int row = g >> 5, pcc = g & 31, lc = pcc ^ row;
    GLL(Ebf + (size_t)row * EF + lc * 8, lds + g * 8);
  }
  __builtin_amdgcn_sched_barrier(0);

  float best_v[2][4];
  int best_i[2][4];
#pragma unroll
  for (int a = 0; a < 2; ++a)
#pragma unroll
    for (int b = 0; b < 4; ++b) { best_v[a][b] = 3.0e38f; best_i[a][b] = 0; }

  int r3 = h * 16 + l15;                  // code row within chunk (0..31)
  unsigned short* eb = lds;               // current buffer (chunk % 3)
  unsigned short* pf = lds + 8192;        // prefetch target ((chunk+1) % 3)
  int c0 = 0;
#pragma unroll 1
  for (int chunk = 0; chunk < 32; ++chunk, c0 += 32) {
    if (chunk < 31) {                     // prefetch chunk+1 (depth 1)
#pragma unroll
      for (int i = 0; i < 2; ++i) {
        int g = i * 512 + tid;
        int row = g >> 5, pcc = g & 31, lc = pcc ^ row;
        GLL(Ebf + (size_t)(c0 + 32 + row) * EF + lc * 8, pf + g * 8);
      }
      __builtin_amdgcn_sched_barrier(0);
      // outstanding = GLL(chunk) [2, oldest] + GLL(chunk+1) [2] -> wait 2
      asm volatile("s_waitcnt vmcnt(2) lgkmcnt(0)\n\ts_barrier" ::: "memory");
    } else {
      asm volatile("s_waitcnt vmcnt(0) lgkmcnt(0)\n\ts_barrier" ::: "memory");
    }
    float en = entab[c0 + r3];            // LDS read (lgkm), outside vm stream
    f32x4 dacc[2];
    dacc[0] = (f32x4){en, en, en, en};
    dacc[1] = (f32x4){en, en, en, en};
    __builtin_amdgcn_s_setprio(1);
#pragma unroll
    for (int kst = 0; kst < 8; ++kst) {
      int cc = kst * 4 + quad;
      int pc = cc ^ r3;
      bf16x8 bfr = *(const bf16x8*)(eb + r3 * 256 + pc * 8);
      dacc[0] = __builtin_amdgcn_mfma_f32_16x16x32_bf16(af[0][kst], bfr, dacc[0], 0, 0, 0);
      dacc[1] = __builtin_amdgcn_mfma_f32_16x16x32_bf16(af[1][kst], bfr, dacc[1], 0, 0, 0);
    }
    __builtin_amdgcn_s_setprio(0);
    int code = c0 + r3;
#pragma unroll
    for (int msub = 0; msub < 2; ++msub)
#pragma unroll
      for (int reg = 0; reg < 4; ++reg) {
        float vv = dacc[msub][reg];
        if (vv < best_v[msub][reg]) { best_v[msub][reg] = vv; best_i[msub][reg] = code; }
      }
    eb = pf;
    pf += 8192;
    if (pf == lds + 24576) pf = lds;      // rotate over 3 buffers
  }

  // ------------------ phase 4: argmin merge, outputs ------------------
#pragma unroll
  for (int msub = 0; msub < 2; ++msub)
#pragma unroll
    for (int reg = 0; reg < 4; ++reg) {
      float vv = best_v[msub][reg];
      int idx = best_i[msub][reg];
#pragma unroll
      for (int off = 8; off; off >>= 1) {
        float ov = __shfl_xor(vv, off, 16);
        int oi = __shfl_xor(idx, off, 16);
        if (ov < vv || (ov == vv && oi < idx)) { vv = ov; idx = oi; }
      }
      best_v[msub][reg] = vv;
      best_i[msub][reg] = idx;
    }
  float* red_v = (float*)lds;            // [2][128]  bytes 0..1023
  int* red_i = (int*)lds + 256;          // [2][128]  bytes 1024..2047
  float* xred = (float*)lds + 512;       // [8]       bytes 2048..2079
  float* svred = (float*)lds + 520;      // [2]       bytes 2080..2087
  int* fidx_w = (int*)lds + 544;         // [128]     bytes 2176..2687
  if (l15 == 0) {
#pragma unroll
    for (int msub = 0; msub < 2; ++msub)
#pragma unroll
      for (int reg = 0; reg < 4; ++reg) {
        int tokloc = g3 * 32 + msub * 16 + quad * 4 + reg;
        red_v[h * 128 + tokloc] = best_v[msub][reg];
        red_i[h * 128 + tokloc] = best_i[msub][reg];
      }
  }
  for (int off = 32; off; off >>= 1) xsq += __shfl_down(xsq, off);
  if (l == 0) xred[w] = xsq;
  __syncthreads();
  if (tid < 128) {
    float v0 = red_v[tid], v1 = red_v[128 + tid];
    int i0 = red_i[tid], i1 = red_i[128 + tid];
    float vv; int idx;
    if (v1 < v0 || (v1 == v0 && i1 < i0)) { vv = v1; idx = i1; } else { vv = v0; idx = i0; }
    fidx_w[tid] = idx;                   // stays in LDS for phase 5
    atomicAdd(&hist[idx], 1u);
    for (int off = 32; off; off >>= 1) vv += __shfl_down(vv, off);
    if ((tid & 63) == 0) svred[tid >> 6] = vv;
  }
  __syncthreads();
  if (tid == 0) {
    float tot = svred[0] + svred[1];
#pragma unroll
    for (int i = 0; i < 8; ++i) tot += xred[i];
    atomicAdd(sse, tot);
  }

  // ------------------ phase 5: fused gather + transposed store ----------
  // embed rows by final index -> out[B][EF][TT], fp32 exact.  zq tile at
  // byte 4096..37375 -- disjoint from red/fidx scalar region (<2688).
  const int* fidx = (const int*)lds + 544;
  float* zq = (float*)lds + 1024;        // [128][65] floats, 33.3 KB
  int bnum = tok0 >> 12, t0 = tok0 & 4095;
  float* outb = out + (((size_t)bnum * EF) << 12) + t0;
#pragma unroll 1
  for (int et = 0; et < 4; ++et) {
    int e0 = et * 64;
#pragma unroll
    for (int rr = 0; rr < 4; ++rr) {
      int tl = rr * 32 + (tid >> 4);
      const float4 g4 = *(const float4*)(embed + (size_t)fidx[tl] * EF + e0 + (tid & 15) * 4);
      float* zr = zq + tl * 65 + (tid & 15) * 4;
      zr[0] = g4.x; zr[1] = g4.y; zr[2] = g4.z; zr[3] = g4.w;
    }
    __syncthreads();
#pragma unroll
    for (int rr = 0; rr < 4; ++rr) {
      int e = rr * 16 + (tid >> 5);
      int tc = (tid & 31) * 4;
      float4 o4;
      o4.x = zq[(tc + 0) * 65 + e];
      o4.y = zq[(tc + 1) * 65 + e];
      o4.z = zq[(tc + 2) * 65 + e];
      o4.w = zq[(tc + 3) * 65 + e];
      *(float4*)(outb + ((size_t)(e0 + e) << 12) + tc) = o4;
    }
    if (et < 3) __syncthreads();
  }
}

// ---------------------------------------------------------------------------
// K3: finalize scalars
// ---------------------------------------------------------------------------
__global__ __launch_bounds__(256) void k_final(const unsigned int* __restrict__ hist,
                                               const float* __restrict__ sse,
                                               float* __restrict__ out) {
  __shared__ float red[4];
  int tid = threadIdx.x;
  float local = 0.f;
  for (int i = tid; i < NE; i += 256) {
    float p = (float)hist[i] * (1.0f / 65536.0f);
    local -= p * logf(p + 1e-10f);
  }
  for (int off = 32; off; off >>= 1) local += __shfl_down(local, off);
  if ((tid & 63) == 0) red[tid >> 6] = local;
  __syncthreads();
  if (tid == 0) {
    float lp = red[0] + red[1] + red[2] + red[3];
    out[16777216] = 1.25f * sse[0] / 16777216.0f;  // vq + 0.25*commitment
    out[16777233] = lp;
  }
  if (tid < 16) out[16777217 + tid] = 6.93147180559945f * 4096.0f;  // log(1024)*4096
}

// ---------------------------------------------------------------------------
extern "C" void kernel_launch(void* const* d_in, const int* in_sizes, int n_in,
                              void* d_out, int out_size, void* d_ws, size_t ws_size,
                              hipStream_t stream) {
  const float* inputs = (const float*)d_in[0];
  const float* proj_w = (const float*)d_in[1];
  const float* proj_b = (const float*)d_in[2];
  const float* embed = (const float*)d_in[3];
  float* out = (float*)d_out;
  char* ws = (char*)d_ws;

  // workspace layout
  unsigned short* Wbf  = (unsigned short*)(ws);            //   262,144 B
  unsigned short* Ebf  = (unsigned short*)(ws + 262144);   //   524,288 B
  float* e_norm        = (float*)(ws + 786432);            //     4,096 B
  unsigned int* hist   = (unsigned int*)(ws + 1052672);    //     4,096 B
  float* sse           = (float*)(ws + 1056768);           //         4 B
  if (ws_size < 1056772) return;

  hipMemsetAsync(ws + 1052672, 0, 4100, stream);  // hist + sse

  k_prep<<<1792, 256, 0, stream>>>(proj_w, embed, Wbf, Ebf, e_norm);
  k_fused<<<512, 512, 0, stream>>>(inputs, Wbf, proj_b, Ebf, e_norm, embed, hist, sse, out);
  k_final<<<1, 256, 0, stream>>>(hist, sse, out);
}